// Round 1
// baseline (104.918 us; speedup 1.0000x reference)
//
#include <hip/hip_runtime.h>

// out[i, :] = corr[i, :] * rsqrt(sum_j corr[i, j]^2)
// DIM = 8192, fp32 in / fp32 out.
//
// One 256-thread block per row. Each thread owns 32 elements (8 x float4)
// kept in registers across the reduction, so the input is read exactly once.
// Traffic: 256 MiB read + 256 MiB write -> memory-bound.

#define DIM 8192
#define TPB 256
#define V4_PER_THREAD (DIM / (TPB * 4))  // 8

__global__ __launch_bounds__(TPB) void row_rescale_kernel(
    const float* __restrict__ in, float* __restrict__ out) {
  const int row = blockIdx.x;
  const float4* rin =
      reinterpret_cast<const float4*>(in + (size_t)row * DIM);
  float4* rout = reinterpret_cast<float4*>(out + (size_t)row * DIM);

  float4 v[V4_PER_THREAD];
  float s = 0.0f;
#pragma unroll
  for (int k = 0; k < V4_PER_THREAD; ++k) {
    v[k] = rin[threadIdx.x + k * TPB];  // coalesced: 16 B/lane, contiguous
    s += v[k].x * v[k].x + v[k].y * v[k].y + v[k].z * v[k].z + v[k].w * v[k].w;
  }

  // Wave-level butterfly reduction (wave = 64 lanes on CDNA!).
#pragma unroll
  for (int off = 32; off > 0; off >>= 1) s += __shfl_xor(s, off, 64);

  // Cross-wave reduction: 4 waves per block.
  __shared__ float wsum[TPB / 64];
  const int lane = threadIdx.x & 63;
  const int wid = threadIdx.x >> 6;
  if (lane == 0) wsum[wid] = s;
  __syncthreads();
  const float tot = wsum[0] + wsum[1] + wsum[2] + wsum[3];
  const float inv = rsqrtf(tot);

#pragma unroll
  for (int k = 0; k < V4_PER_THREAD; ++k) {
    v[k].x *= inv;
    v[k].y *= inv;
    v[k].z *= inv;
    v[k].w *= inv;
    rout[threadIdx.x + k * TPB] = v[k];
  }
}

extern "C" void kernel_launch(void* const* d_in, const int* in_sizes, int n_in,
                              void* d_out, int out_size, void* d_ws,
                              size_t ws_size, hipStream_t stream) {
  const float* corr = (const float*)d_in[0];
  float* out = (float*)d_out;
  row_rescale_kernel<<<DIM, TPB, 0, stream>>>(corr, out);
}

// Round 3
// 96.339 us; speedup vs baseline: 1.0890x; 1.0890x over previous
//
#include <hip/hip_runtime.h>

// out[i, :] = corr[i, :] * rsqrt(sum_j corr[i, j]^2)
// DIM = 8192, fp32 in / fp32 out.
//
// One 256-thread block per row. Each thread owns 32 elements (8 x f32x4)
// kept in registers across the reduction, so the input is read exactly once.
// Traffic: 256 MiB read + 256 MiB write -> memory-bound.
//
// R2 change: non-temporal builtins need clang native vectors, not the
// HIP_vector_type struct -- use ext_vector_type(4) float.

#define DIM 8192
#define TPB 256
#define V4_PER_THREAD (DIM / (TPB * 4))  // 8

typedef __attribute__((ext_vector_type(4))) float f32x4;

__global__ __launch_bounds__(TPB) void row_rescale_kernel(
    const float* __restrict__ in, float* __restrict__ out) {
  const int row = blockIdx.x;
  const f32x4* rin = reinterpret_cast<const f32x4*>(in + (size_t)row * DIM);
  f32x4* rout = reinterpret_cast<f32x4*>(out + (size_t)row * DIM);

  f32x4 v[V4_PER_THREAD];
  float s0 = 0.0f, s1 = 0.0f;
#pragma unroll
  for (int k = 0; k < V4_PER_THREAD; ++k) {
    v[k] = __builtin_nontemporal_load(rin + threadIdx.x + k * TPB);
    // two accumulators to break the FMA dependency chain
    if (k & 1)
      s1 += v[k].x * v[k].x + v[k].y * v[k].y + v[k].z * v[k].z + v[k].w * v[k].w;
    else
      s0 += v[k].x * v[k].x + v[k].y * v[k].y + v[k].z * v[k].z + v[k].w * v[k].w;
  }
  float s = s0 + s1;

  // Wave-level butterfly reduction (wave = 64 lanes on CDNA!).
#pragma unroll
  for (int off = 32; off > 0; off >>= 1) s += __shfl_xor(s, off, 64);

  // Cross-wave reduction: 4 waves per block.
  __shared__ float wsum[TPB / 64];
  const int lane = threadIdx.x & 63;
  const int wid = threadIdx.x >> 6;
  if (lane == 0) wsum[wid] = s;
  __syncthreads();
  const float tot = wsum[0] + wsum[1] + wsum[2] + wsum[3];
  const float inv = rsqrtf(tot);

#pragma unroll
  for (int k = 0; k < V4_PER_THREAD; ++k) {
    f32x4 o = v[k] * inv;
    __builtin_nontemporal_store(o, rout + threadIdx.x + k * TPB);
  }
}

extern "C" void kernel_launch(void* const* d_in, const int* in_sizes, int n_in,
                              void* d_out, int out_size, void* d_ws,
                              size_t ws_size, hipStream_t stream) {
  const float* corr = (const float*)d_in[0];
  float* out = (float*)d_out;
  row_rescale_kernel<<<DIM, TPB, 0, stream>>>(corr, out);
}

// Round 4
// 82.281 us; speedup vs baseline: 1.2751x; 1.1709x over previous
//
#include <hip/hip_runtime.h>

// out[i, :] = corr[i, :] * rsqrt(sum_j corr[i, j]^2)
// DIM = 8192, fp32 in / fp32 out.
//
// One 256-thread block per row; each thread holds 32 elements in registers,
// one read + one write per element. Memory-bound.
//
// R3 change: TEMPORAL loads + non-temporal stores. Input (256 MiB) == L3
// size; letting loads allocate in Infinity Cache while stores bypass it
// should keep the input L3-resident across graph replays -> reads at L3 BW,
// HBM services only the write stream (fills sustain ~7 TB/s write-only).

#define DIM 8192
#define TPB 256
#define V4_PER_THREAD (DIM / (TPB * 4))  // 8

typedef __attribute__((ext_vector_type(4))) float f32x4;

__global__ __launch_bounds__(TPB) void row_rescale_kernel(
    const float* __restrict__ in, float* __restrict__ out) {
  const int row = blockIdx.x;
  const f32x4* rin = reinterpret_cast<const f32x4*>(in + (size_t)row * DIM);
  f32x4* rout = reinterpret_cast<f32x4*>(out + (size_t)row * DIM);

  f32x4 v[V4_PER_THREAD];
  float s0 = 0.0f, s1 = 0.0f;
#pragma unroll
  for (int k = 0; k < V4_PER_THREAD; ++k) {
    v[k] = rin[threadIdx.x + k * TPB];  // temporal: allocate in L2/L3
    if (k & 1)
      s1 += v[k].x * v[k].x + v[k].y * v[k].y + v[k].z * v[k].z + v[k].w * v[k].w;
    else
      s0 += v[k].x * v[k].x + v[k].y * v[k].y + v[k].z * v[k].z + v[k].w * v[k].w;
  }
  float s = s0 + s1;

  // Wave-level butterfly reduction (wave = 64 lanes on CDNA!).
#pragma unroll
  for (int off = 32; off > 0; off >>= 1) s += __shfl_xor(s, off, 64);

  // Cross-wave reduction: 4 waves per block.
  __shared__ float wsum[TPB / 64];
  const int lane = threadIdx.x & 63;
  const int wid = threadIdx.x >> 6;
  if (lane == 0) wsum[wid] = s;
  __syncthreads();
  const float tot = wsum[0] + wsum[1] + wsum[2] + wsum[3];
  const float inv = rsqrtf(tot);

#pragma unroll
  for (int k = 0; k < V4_PER_THREAD; ++k) {
    f32x4 o = v[k] * inv;
    __builtin_nontemporal_store(o, rout + threadIdx.x + k * TPB);  // bypass
  }
}

extern "C" void kernel_launch(void* const* d_in, const int* in_sizes, int n_in,
                              void* d_out, int out_size, void* d_ws,
                              size_t ws_size, hipStream_t stream) {
  const float* corr = (const float*)d_in[0];
  float* out = (float*)d_out;
  row_rescale_kernel<<<DIM, TPB, 0, stream>>>(corr, out);
}